// Round 12
// baseline (412.248 us; speedup 1.0000x reference)
//
#include <hip/hip_runtime.h>

// Problem constants
#define BATCH 4
#define CH    64
#define HH    64
#define WW    64
#define LL    4096          // HH*WW
#define SPLITS 4
#define RPS   1024          // LL/SPLITS
#define NRT   4             // r-tiles of 256 per block

// LDS K-tile buffer: per side 256 rows x 112 B (7 granules: 6 data + 1 dummy)
#define RSTB  112
#define BUFB  57344         // bytes per stage buffer (A 28KB | B 28KB)
#define BSOFF 28672         // B side byte offset within buffer
#define CSTRIDE 139392      // 16-ch group stride: 2*PAD_L*16

// Padded pre-split global image Gp[side][b][comp][c8(8)][4356][8ch] (ushort)
#define PAD_L   4356        // 66*66
#define GP_BYTE_BASE 1048576
#define GP_SIDE_STRIDE 6690816   // 4*3*8*4356*8*2
#define GP_B_STRIDE    1672704   // 3*8*4356*8*2
#define GP_COMP_STRIDE 557568    // 8*4356*16
#define GP_TOTAL       13381632  // 2*GP_SIDE_STRIDE

// Workspace layout (float words)
#define WS_SSQ_RS 0
#define WS_SSQ_LR 16384
#define WS_INV_RS 32768
#define WS_INV_LR 49152
#define WS_PMAX   65536      // [B*SPLITS*L] = 65536
#define WS_PARG   131072     // [B*SPLITS*L] = 65536
#define WS_ARG    196608     // [B*L]

typedef __attribute__((ext_vector_type(8))) short short8b;
typedef __attribute__((ext_vector_type(4))) float f32x4;
typedef __attribute__((ext_vector_type(16))) float f32x16;

__device__ __forceinline__ void gload16(const void* g, void* l) {
    __builtin_amdgcn_global_load_lds(
        (const __attribute__((address_space(1))) unsigned int*)g,
        (__attribute__((address_space(3))) unsigned int*)l, 16, 0, 0);
}

// -------- 0) pre-split: fp32 -> 3 truncated bf16 comps, padded image --------
__global__ void k_split(const float* __restrict__ lrsr,
                        const float* __restrict__ refsr,
                        float* __restrict__ ws) {
    int tid  = threadIdx.x;
    int pos  = blockIdx.x * 256 + tid;          // 0..4095
    int c8   = blockIdx.y;                      // 0..7
    int side = blockIdx.z >> 2;                 // 0 = refsr(A), 1 = lrsr(B)
    int b    = blockIdx.z & 3;
    const float* src = (side ? lrsr : refsr) + (size_t)b * CH * LL + c8 * 8 * LL + pos;
    int ppos = (pos >> 6) * 66 + (pos & 63) + 67;   // (y+1)*66 + (x+1)
    char* dst = (char*)ws + GP_BYTE_BASE + side * GP_SIDE_STRIDE + b * GP_B_STRIDE
              + (size_t)(c8 * PAD_L + ppos) * 16;
    union { unsigned short u[8]; uint4 v; } w0, w1, w2;
    #pragma unroll
    for (int cc = 0; cc < 8; ++cc) {
        float x = src[cc * LL];
        unsigned u0 = __float_as_uint(x);
        float f0 = __uint_as_float(u0 & 0xffff0000u);
        float r1 = x - f0;
        unsigned u1 = __float_as_uint(r1);
        float f1 = __uint_as_float(u1 & 0xffff0000u);
        float r2 = r1 - f1;
        w0.u[cc] = (unsigned short)(u0 >> 16);
        w1.u[cc] = (unsigned short)(u1 >> 16);
        w2.u[cc] = (unsigned short)(__float_as_uint(r2) >> 16);
    }
    *(uint4*)(dst)                      = w0.v;
    *(uint4*)(dst + GP_COMP_STRIDE)     = w1.v;
    *(uint4*)(dst + 2 * GP_COMP_STRIDE) = w2.v;
}

// -------- 1) channel sum-of-squares per position (both inputs) --------
__global__ void k_ssq(const float* __restrict__ lrsr,
                      const float* __restrict__ refsr,
                      float* __restrict__ ws) {
    int t = blockIdx.x * 256 + threadIdx.x;      // 0..B*L-1
    int b = t >> 12;
    int r = t & (LL - 1);
    const float* pl = lrsr + (size_t)b * CH * LL + r;
    const float* pr = refsr + (size_t)b * CH * LL + r;
    float sl = 0.f, sr = 0.f;
    #pragma unroll 8
    for (int c = 0; c < CH; ++c) {
        float a = pl[c * LL]; sl += a * a;
        float d = pr[c * LL]; sr += d * d;
    }
    ws[WS_SSQ_RS + t] = sr;
    ws[WS_SSQ_LR + t] = sl;
}

// -------- 2) 3x3 box-sum of ssq (zero pad) -> 1/max(norm,eps) --------
__global__ void k_inv(float* __restrict__ ws) {
    int t = blockIdx.x * 256 + threadIdx.x;      // 0..B*L-1
    int b = t >> 12;
    int r = t & (LL - 1);
    int y = r >> 6, x = r & 63;
    float srs = 0.f, slr = 0.f;
    for (int di = -1; di <= 1; ++di) {
        int yy = y + di;
        if ((unsigned)yy >= (unsigned)HH) continue;
        for (int dj = -1; dj <= 1; ++dj) {
            int xx = x + dj;
            if ((unsigned)xx >= (unsigned)WW) continue;
            int idx = b * LL + yy * WW + xx;
            srs += ws[WS_SSQ_RS + idx];
            slr += ws[WS_SSQ_LR + idx];
        }
    }
    ws[WS_INV_RS + t] = 1.f / fmaxf(sqrtf(srs), 1e-12f);
    ws[WS_INV_LR + t] = 1.f / fmaxf(sqrtf(slr), 1e-12f);
}

// -------- 3) MFMA corr GEMM: 256x256, dbuf, 4-phase K-tile pipeline ---------
// Tile boundary: __syncthreads (vmcnt drain of tile-old DMA + buffer safety).
// Within tile: 4 phases, raw s_barrier pacing; phase p issues A-frag reads
// for phase p+1, then runs 12 MFMA on operands read one phase earlier ->
// LDS port time hides under the MFMA pipe instead of serializing.
__global__ __launch_bounds__(512, 2)
void k_corrmax(float* __restrict__ ws) {
    __shared__ __align__(16) char LDSB[2 * BUFB];   // 112 KB double buffer

    int tid  = threadIdx.x;
    int L    = blockIdx.x;                 // 0..255
    int xcd  = L & 7;
    int slot = L >> 3;
    int b    = xcd >> 1;
    int bx   = slot >> 1;                  // 0..15
    int by   = ((xcd & 1) << 1) | (slot & 1);   // 0..3
    int l0   = bx * 256;
    int rbs  = by * RPS;

    int lane = tid & 63;
    int w    = __builtin_amdgcn_readfirstlane(tid >> 6);   // scalar wave id
    int wr   = w >> 2;          // r half 0..1 (128 rows)
    int wc   = w & 3;           // l quarter 0..3 (64 cols)
    int l31  = lane & 31;
    int g2   = lane >> 5;       // k-octet selector

    const float* invn_rs = ws + WS_INV_RS + b * LL;
    const char*  gpB = (const char*)ws + GP_BYTE_BASE + b * GP_B_STRIDE;

    // ---- staging constants: 7 granules per thread (3584 = 512*7) ----
    int LC[7];
    int sideF[7];
    #pragma unroll
    for (int n = 0; n < 7; ++n) {
        int G    = n * 512 + tid;
        int side = (n * 8 + w >= 28) ? 1 : 0;
        int gg   = G - side * 1792;
        int row  = gg / 7;
        int slot2 = gg - row * 7;
        int comp = (slot2 >= 6) ? 0 : (slot2 >> 1);
        int oct  = (slot2 >= 6) ? 0 : (slot2 & 1);
        LC[n] = side * GP_SIDE_STRIDE + comp * GP_COMP_STRIDE + oct * (PAD_L * 16)
              + (row + 2 * (row >> 6)) * 16;
        sideF[n] = side;
    }

    // ---- fragment LDS byte bases (mf adds +32*RSTB, comp c adds +c*32) ----
    int abase = (wr * 128 + l31) * RSTB + g2 * 16;
    int bbase = BSOFF + (wc * 64 + l31) * RSTB + g2 * 16;

    int ybA = by * 16;          // A-side y base
    int ybB = bx * 4;           // B-side y base

    auto issue = [&](int rt2, int q2, int m2, int bufo) {
        int i2 = (q2 < 3) ? -1 : ((q2 < 6) ? 0 : 1);
        int j2 = q2 - (i2 + 1) * 3 - 1;
        int suA = ((ybA + rt2 * 4 + 1 + i2) * 66 + 1 + j2) * 16 + m2 * CSTRIDE;
        int suB = ((ybB + 1 + i2) * 66 + 1 + j2) * 16 + m2 * CSTRIDE;
        #pragma unroll
        for (int n = 0; n < 7; ++n) {
            int su = sideF[n] ? suB : suA;   // wave-uniform select
            gload16(gpB + (LC[n] + su), LDSB + bufo + n * 8192 + tid * 16);
        }
    };

    float rm[2] = {-1e30f, -1e30f};   // running max per nf column
    int   ra[2] = {0, 0};

    issue(0, 0, 0, 0);
    int cur = 0;

    for (int rt = 0; rt < NRT; ++rt) {
        int r0 = rbs + rt * 256;

        f32x16 acc[4][2];
        #pragma unroll
        for (int mf = 0; mf < 4; ++mf)
            #pragma unroll
            for (int nf = 0; nf < 2; ++nf)
                #pragma unroll
                for (int e = 0; e < 16; ++e) acc[mf][nf][e] = 0.f;

        for (int q = 0; q < 9; ++q) {
            for (int m = 0; m < 4; ++m) {
                __syncthreads();   // vmcnt drain (tile-old loads) + buffer safety
                // ---- issue next K-tile into the other buffer ----
                {
                    int m2 = m + 1, q2 = q, rt2 = rt;
                    if (m2 == 4) { m2 = 0; ++q2; if (q2 == 9) { q2 = 0; ++rt2; } }
                    if (rt2 < NRT) issue(rt2, q2, m2, (cur ^ 1) * BUFB);
                }
                const char* lb = LDSB + cur * BUFB;
                // ---- B frags (used all phases) + A frags for phase 0 ----
                short8b bfr[2][3];
                #pragma unroll
                for (int nf = 0; nf < 2; ++nf)
                    #pragma unroll
                    for (int c = 0; c < 3; ++c)
                        bfr[nf][c] = *(const short8b*)(lb + bbase + nf * (32 * RSTB) + c * 32);
                short8b afr[2][3];     // phase-ahead double slot
                #pragma unroll
                for (int c = 0; c < 3; ++c)
                    afr[0][c] = *(const short8b*)(lb + abase + c * 32);
                // ---- 4 phases: pacing barrier, prefetch next A, 12 MFMA ----
                #pragma unroll
                for (int mf = 0; mf < 4; ++mf) {
                    __builtin_amdgcn_s_barrier();
                    if (mf < 3) {
                        #pragma unroll
                        for (int c = 0; c < 3; ++c)
                            afr[(mf + 1) & 1][c] =
                                *(const short8b*)(lb + abase + (mf + 1) * (32 * RSTB) + c * 32);
                    }
                    __builtin_amdgcn_s_setprio(1);
                    #pragma unroll
                    for (int nf = 0; nf < 2; ++nf) {
                        f32x16 d = acc[mf][nf];
                        d = __builtin_amdgcn_mfma_f32_32x32x16_bf16(afr[mf & 1][0], bfr[nf][0], d, 0, 0, 0);
                        d = __builtin_amdgcn_mfma_f32_32x32x16_bf16(afr[mf & 1][0], bfr[nf][1], d, 0, 0, 0);
                        d = __builtin_amdgcn_mfma_f32_32x32x16_bf16(afr[mf & 1][1], bfr[nf][0], d, 0, 0, 0);
                        d = __builtin_amdgcn_mfma_f32_32x32x16_bf16(afr[mf & 1][1], bfr[nf][1], d, 0, 0, 0);
                        d = __builtin_amdgcn_mfma_f32_32x32x16_bf16(afr[mf & 1][0], bfr[nf][2], d, 0, 0, 0);
                        d = __builtin_amdgcn_mfma_f32_32x32x16_bf16(afr[mf & 1][2], bfr[nf][0], d, 0, 0, 0);
                        acc[mf][nf] = d;
                    }
                    __builtin_amdgcn_s_setprio(0);
                }
                cur ^= 1;
            }
        }

        // ---- epilogue (registers only) ----
        // C layout: col = lane&31, row = (reg&3) + 8*(reg>>2) + 4*(lane>>5)
        #pragma unroll
        for (int mf = 0; mf < 4; ++mf) {
            f32x4 iv[4];
            #pragma unroll
            for (int rb = 0; rb < 4; ++rb)
                iv[rb] = *(const f32x4*)&invn_rs[r0 + wr * 128 + mf * 32 + g2 * 4 + rb * 8];
            #pragma unroll
            for (int nf = 0; nf < 2; ++nf)
                #pragma unroll
                for (int reg = 0; reg < 16; ++reg) {
                    int r = r0 + wr * 128 + mf * 32 + (reg & 3) + 8 * (reg >> 2) + 4 * g2;
                    float val = acc[mf][nf][reg] * iv[reg >> 2][reg & 3];
                    if (val > rm[nf] || (val == rm[nf] && r < ra[nf])) { rm[nf] = val; ra[nf] = r; }
                }
        }
    }

    // ---- lane-pair merge (lanes l, l+32 hold same column) ----
    #pragma unroll
    for (int nf = 0; nf < 2; ++nf) {
        float ov = __shfl_xor(rm[nf], 32);
        int   oi = __shfl_xor(ra[nf], 32);
        if (ov > rm[nf] || (ov == rm[nf] && oi < ra[nf])) { rm[nf] = ov; ra[nf] = oi; }
    }
    // ---- cross-wave merge (DMA fully drained: nothing issued after last tile) ----
    __syncthreads();
    float* sm2 = (float*)LDSB;          // [2][256]
    int*   si2 = (int*)LDSB + 512;      // [2][256]
    if (lane < 32) {
        #pragma unroll
        for (int nf = 0; nf < 2; ++nf) {
            sm2[wr * 256 + wc * 64 + nf * 32 + l31] = rm[nf];
            si2[wr * 256 + wc * 64 + nf * 32 + l31] = ra[nf];
        }
    }
    __syncthreads();
    if (tid < 256) {
        float bm = sm2[tid]; int ba = si2[tid];
        float v  = sm2[256 + tid]; int a2 = si2[256 + tid];
        if (v > bm || (v == bm && a2 < ba)) { bm = v; ba = a2; }
        int l = l0 + tid;
        int o = (b * SPLITS + by) * LL + l;
        ws[WS_PMAX + o] = bm;
        ((int*)ws)[WS_PARG + o] = ba;
    }
}

// -------- 4) reduce over splits -> s output + final argmax --------
__global__ void k_reduce(float* __restrict__ ws, float* __restrict__ out) {
    int t = blockIdx.x * 256 + threadIdx.x;   // 0..B*L-1
    int b = t >> 12;
    int l = t & (LL - 1);
    float bm = -1e30f; int ba = 0;
    for (int s = 0; s < SPLITS; ++s) {        // splits are ascending r ranges
        int o = (b * SPLITS + s) * LL + l;
        float v = ws[WS_PMAX + o];
        int   a = ((int*)ws)[WS_PARG + o];
        if (v > bm || (v == bm && a < ba)) { bm = v; ba = a; }
    }
    out[t] = bm * ws[WS_INV_LR + t];          // s: [B,1,H,W] flat
    ((int*)ws)[WS_ARG + t] = ba;
}

// -------- 5) gather from ref via argmax + fold(3x3, pad 1) --------
__global__ void k_fold(const float* __restrict__ ref,
                       const float* __restrict__ ws,
                       float* __restrict__ out) {
    int t = blockIdx.x * 256 + threadIdx.x;   // 0..B*C*L-1
    int b = t >> 18;
    int c = (t >> 12) & 63;
    int yx = t & (LL - 1);
    int y = yx >> 6, x = yx & 63;
    const int* ab = ((const int*)ws) + WS_ARG + b * LL;
    const float* rb = ref + (size_t)b * CH * LL + c * LL;
    float s = 0.f;
    #pragma unroll
    for (int i = 0; i < 3; ++i) {
        int yp = y + 1 - i;
        if ((unsigned)yp >= (unsigned)HH) continue;
        #pragma unroll
        for (int j = 0; j < 3; ++j) {
            int xp = x + 1 - j;
            if ((unsigned)xp >= (unsigned)WW) continue;
            int r = ab[yp * WW + xp];
            int ry = (r >> 6) + i - 1;
            int rx = (r & 63) + j - 1;
            if ((unsigned)ry < (unsigned)HH && (unsigned)rx < (unsigned)WW)
                s += rb[ry * WW + rx];
        }
    }
    out[BATCH * LL + t] = s;                  // trans after s (16384 floats)
}

extern "C" void kernel_launch(void* const* d_in, const int* in_sizes, int n_in,
                              void* d_out, int out_size, void* d_ws, size_t ws_size,
                              hipStream_t stream) {
    const float* lrsr = (const float*)d_in[0];
    const float* refsr = (const float*)d_in[1];
    const float* ref  = (const float*)d_in[2];
    float* out = (float*)d_out;
    float* ws  = (float*)d_ws;

    // zero the padded pre-split region (borders must be 0)
    hipMemsetAsync((char*)d_ws + GP_BYTE_BASE, 0, GP_TOTAL, stream);
    k_split<<<dim3(16, 8, 8), dim3(256), 0, stream>>>(lrsr, refsr, ws);
    k_ssq<<<dim3(BATCH * LL / 256), dim3(256), 0, stream>>>(lrsr, refsr, ws);
    k_inv<<<dim3(BATCH * LL / 256), dim3(256), 0, stream>>>(ws);
    k_corrmax<<<dim3(256), dim3(512), 0, stream>>>(ws);
    k_reduce<<<dim3(BATCH * LL / 256), dim3(256), 0, stream>>>(ws, out);
    k_fold<<<dim3(BATCH * CH * LL / 256), dim3(256), 0, stream>>>(ref, ws, out);
}

// Round 13
// 376.170 us; speedup vs baseline: 1.0959x; 1.0959x over previous
//
#include <hip/hip_runtime.h>

// Problem constants
#define BATCH 4
#define CH    64
#define HH    64
#define WW    64
#define LL    4096          // HH*WW
#define SPLITS 4
#define RPS   1024          // LL/SPLITS
#define NRT   4             // r-tiles of 256 per block

// LDS K-tile buffer, [slot][pos] layout: 6 slots (3 comps x 2 octets) x 256
// positions x 16B. A side slots 0-5 (24KB), B side slots 0-5 (24KB) -> 48KB.
// Triple-buffered: 144 KB total, prefetch distance 2, counted vmcnt.
#define BUFB  49152         // bytes per stage buffer
#define BSOFF 24576         // B side byte offset within buffer
#define NBUF3 147456        // 3*BUFB
#define CSTRIDE 139392      // 16-ch group stride: 2*PAD_L*16

// Padded pre-split global image Gp[side][b][comp][c8(8)][4356][8ch] (ushort)
#define PAD_L   4356        // 66*66
#define GP_BYTE_BASE 1048576
#define GP_SIDE_STRIDE 6690816   // 4*3*8*4356*8*2
#define GP_B_STRIDE    1672704   // 3*8*4356*8*2
#define GP_COMP_STRIDE 557568    // 8*4356*16
#define GP_TOTAL       13381632  // 2*GP_SIDE_STRIDE

// Workspace layout (float words)
#define WS_SSQ_RS 0
#define WS_SSQ_LR 16384
#define WS_INV_RS 32768
#define WS_INV_LR 49152
#define WS_PMAX   65536      // [B*SPLITS*L] = 65536
#define WS_PARG   131072     // [B*SPLITS*L] = 65536
#define WS_ARG    196608     // [B*L]

typedef __attribute__((ext_vector_type(8))) short short8b;
typedef __attribute__((ext_vector_type(4))) float f32x4;
typedef __attribute__((ext_vector_type(16))) float f32x16;

__device__ __forceinline__ void gload16(const void* g, void* l) {
    __builtin_amdgcn_global_load_lds(
        (const __attribute__((address_space(1))) unsigned int*)g,
        (__attribute__((address_space(3))) unsigned int*)l, 16, 0, 0);
}

// -------- 0) pre-split: fp32 -> 3 truncated bf16 comps, padded image --------
__global__ void k_split(const float* __restrict__ lrsr,
                        const float* __restrict__ refsr,
                        float* __restrict__ ws) {
    int tid  = threadIdx.x;
    int pos  = blockIdx.x * 256 + tid;          // 0..4095
    int c8   = blockIdx.y;                      // 0..7
    int side = blockIdx.z >> 2;                 // 0 = refsr(A), 1 = lrsr(B)
    int b    = blockIdx.z & 3;
    const float* src = (side ? lrsr : refsr) + (size_t)b * CH * LL + c8 * 8 * LL + pos;
    int ppos = (pos >> 6) * 66 + (pos & 63) + 67;   // (y+1)*66 + (x+1)
    char* dst = (char*)ws + GP_BYTE_BASE + side * GP_SIDE_STRIDE + b * GP_B_STRIDE
              + (size_t)(c8 * PAD_L + ppos) * 16;
    union { unsigned short u[8]; uint4 v; } w0, w1, w2;
    #pragma unroll
    for (int cc = 0; cc < 8; ++cc) {
        float x = src[cc * LL];
        unsigned u0 = __float_as_uint(x);
        float f0 = __uint_as_float(u0 & 0xffff0000u);
        float r1 = x - f0;
        unsigned u1 = __float_as_uint(r1);
        float f1 = __uint_as_float(u1 & 0xffff0000u);
        float r2 = r1 - f1;
        w0.u[cc] = (unsigned short)(u0 >> 16);
        w1.u[cc] = (unsigned short)(u1 >> 16);
        w2.u[cc] = (unsigned short)(__float_as_uint(r2) >> 16);
    }
    *(uint4*)(dst)                      = w0.v;
    *(uint4*)(dst + GP_COMP_STRIDE)     = w1.v;
    *(uint4*)(dst + 2 * GP_COMP_STRIDE) = w2.v;
}

// -------- 1) channel sum-of-squares per position (both inputs) --------
__global__ void k_ssq(const float* __restrict__ lrsr,
                      const float* __restrict__ refsr,
                      float* __restrict__ ws) {
    int t = blockIdx.x * 256 + threadIdx.x;      // 0..B*L-1
    int b = t >> 12;
    int r = t & (LL - 1);
    const float* pl = lrsr + (size_t)b * CH * LL + r;
    const float* pr = refsr + (size_t)b * CH * LL + r;
    float sl = 0.f, sr = 0.f;
    #pragma unroll 8
    for (int c = 0; c < CH; ++c) {
        float a = pl[c * LL]; sl += a * a;
        float d = pr[c * LL]; sr += d * d;
    }
    ws[WS_SSQ_RS + t] = sr;
    ws[WS_SSQ_LR + t] = sl;
}

// -------- 2) 3x3 box-sum of ssq (zero pad) -> 1/max(norm,eps) --------
__global__ void k_inv(float* __restrict__ ws) {
    int t = blockIdx.x * 256 + threadIdx.x;      // 0..B*L-1
    int b = t >> 12;
    int r = t & (LL - 1);
    int y = r >> 6, x = r & 63;
    float srs = 0.f, slr = 0.f;
    for (int di = -1; di <= 1; ++di) {
        int yy = y + di;
        if ((unsigned)yy >= (unsigned)HH) continue;
        for (int dj = -1; dj <= 1; ++dj) {
            int xx = x + dj;
            if ((unsigned)xx >= (unsigned)WW) continue;
            int idx = b * LL + yy * WW + xx;
            srs += ws[WS_SSQ_RS + idx];
            slr += ws[WS_SSQ_LR + idx];
        }
    }
    ws[WS_INV_RS + t] = 1.f / fmaxf(sqrtf(srs), 1e-12f);
    ws[WS_INV_LR + t] = 1.f / fmaxf(sqrtf(slr), 1e-12f);
}

// -------- 3) MFMA corr GEMM: 256x256, [slot][pos] LDS, 3-buf counted vmcnt --
// Per tile t: vmcnt(6) [own tile-t loads done] -> s_barrier [ALL waves' tile-t
// loads done; buf[(t+2)%3] free] -> issue(t+2) -> ds_read frags (lane-
// contiguous 16B, conflict-free, compile-time offsets) -> MFMA. One barrier
// per tile; DMA has ~2 tiles of time in flight, never drained mid-loop.
__global__ __launch_bounds__(512, 2)
void k_corrmax(float* __restrict__ ws) {
    __shared__ __align__(16) char LDSB[NBUF3];   // 144 KB triple buffer

    int tid  = threadIdx.x;
    int L    = blockIdx.x;                 // 0..255
    int xcd  = L & 7;
    int slt  = L >> 3;
    int b    = xcd >> 1;
    int bx   = slt >> 1;                   // 0..15
    int by   = ((xcd & 1) << 1) | (slt & 1);    // 0..3
    int l0   = bx * 256;
    int rbs  = by * RPS;

    int lane = tid & 63;
    int w    = __builtin_amdgcn_readfirstlane(tid >> 6);   // scalar wave id
    int wr   = w >> 2;          // r half 0..1 (128 rows)
    int wc   = w & 3;           // l quarter 0..3 (64 cols)
    int l31  = lane & 31;
    int g2   = lane >> 5;       // k-octet selector

    const float* invn_rs = ws + WS_INV_RS + b * LL;
    const char*  gpB = (const char*)ws + GP_BYTE_BASE + b * GP_B_STRIDE;

    // ---- staging constants: 6 granules/thread; G = n*512+tid; side = n>=3 ----
    // LDS granule G -> [side][slot = (G-side*1536)>>8][pos = G&255]
    int LC[6];
    #pragma unroll
    for (int n = 0; n < 6; ++n) {
        int side = (n >= 3) ? 1 : 0;
        int gg   = n * 512 + tid - side * 1536;
        int slot = gg >> 8;
        int pos  = gg & 255;
        LC[n] = side * GP_SIDE_STRIDE + (slot >> 1) * GP_COMP_STRIDE
              + (slot & 1) * (PAD_L * 16) + (pos + 2 * (pos >> 6)) * 16;
    }

    // ---- fragment bases: addr = base + c*8192 + frag*512 (imm offsets) ----
    int abase = g2 * 4096 + (wr * 128 + l31) * 16;
    int bbase = BSOFF + g2 * 4096 + (wc * 64 + l31) * 16;

    int ybA = by * 16;          // A-side y base
    int ybB = bx * 4;           // B-side y base

    auto issue = [&](int rt2, int q2, int m2, int bufo) {
        int i2 = (q2 < 3) ? -1 : ((q2 < 6) ? 0 : 1);
        int j2 = q2 - (i2 + 1) * 3 - 1;
        int suA = ((ybA + rt2 * 4 + 1 + i2) * 66 + 1 + j2) * 16 + m2 * CSTRIDE;
        int suB = ((ybB + 1 + i2) * 66 + 1 + j2) * 16 + m2 * CSTRIDE;
        #pragma unroll
        for (int n = 0; n < 6; ++n) {
            int su = (n >= 3) ? suB : suA;   // compile-time select per n
            gload16(gpB + (LC[n] + su), LDSB + bufo + n * 8192 + tid * 16);
        }
    };

    float rm[2] = {-1e30f, -1e30f};   // running max per nf column
    int   ra[2] = {0, 0};

    // ---- prologue: tiles 0 and 1 in flight ----
    issue(0, 0, 0, 0);
    issue(0, 0, 1, BUFB);
    int ibrt = 0, ibq = 0, ibm = 2;   // next tile to issue = (0,0,2)
    int bufn = 2 * BUFB;              // its buffer
    int bufc = 0;                     // current tile's buffer

    for (int rt = 0; rt < NRT; ++rt) {
        int r0 = rbs + rt * 256;

        f32x16 acc[4][2];
        #pragma unroll
        for (int mf = 0; mf < 4; ++mf)
            #pragma unroll
            for (int nf = 0; nf < 2; ++nf)
                #pragma unroll
                for (int e = 0; e < 16; ++e) acc[mf][nf][e] = 0.f;

        for (int q = 0; q < 9; ++q) {
            for (int m = 0; m < 4; ++m) {
                // ---- counted wait: own tile-t loads complete (6 newer remain)
                if (rt == NRT - 1 && q == 8 && m == 3)
                    asm volatile("s_waitcnt vmcnt(0)" ::: "memory");
                else
                    asm volatile("s_waitcnt vmcnt(6)" ::: "memory");
                __builtin_amdgcn_s_barrier();   // all waves' tile-t loads done

                // ---- issue tile t+2 into the buffer freed at tile t-1 ----
                if (ibrt < NRT) {
                    issue(ibrt, ibq, ibm, bufn);
                    ++ibm;
                    if (ibm == 4) { ibm = 0; ++ibq; if (ibq == 9) { ibq = 0; ++ibrt; } }
                    bufn += BUFB; if (bufn == NBUF3) bufn = 0;
                }

                // ---- fragments + 6-product MFMA from current buffer ----
                const char* lb = LDSB + bufc;
                short8b bfr[2][3];
                #pragma unroll
                for (int nf = 0; nf < 2; ++nf)
                    #pragma unroll
                    for (int c = 0; c < 3; ++c)
                        bfr[nf][c] = *(const short8b*)(lb + bbase + c * 8192 + nf * 512);
                #pragma unroll
                for (int mfh = 0; mfh < 2; ++mfh) {
                    short8b afr[2][3];
                    #pragma unroll
                    for (int mi = 0; mi < 2; ++mi)
                        #pragma unroll
                        for (int c = 0; c < 3; ++c)
                            afr[mi][c] = *(const short8b*)(lb + abase + c * 8192 + (mfh * 2 + mi) * 512);
                    __builtin_amdgcn_s_setprio(1);
                    #pragma unroll
                    for (int mi = 0; mi < 2; ++mi)
                        #pragma unroll
                        for (int nf = 0; nf < 2; ++nf) {
                            f32x16 d = acc[mfh * 2 + mi][nf];
                            d = __builtin_amdgcn_mfma_f32_32x32x16_bf16(afr[mi][0], bfr[nf][0], d, 0, 0, 0);
                            d = __builtin_amdgcn_mfma_f32_32x32x16_bf16(afr[mi][0], bfr[nf][1], d, 0, 0, 0);
                            d = __builtin_amdgcn_mfma_f32_32x32x16_bf16(afr[mi][1], bfr[nf][0], d, 0, 0, 0);
                            d = __builtin_amdgcn_mfma_f32_32x32x16_bf16(afr[mi][1], bfr[nf][1], d, 0, 0, 0);
                            d = __builtin_amdgcn_mfma_f32_32x32x16_bf16(afr[mi][0], bfr[nf][2], d, 0, 0, 0);
                            d = __builtin_amdgcn_mfma_f32_32x32x16_bf16(afr[mi][2], bfr[nf][0], d, 0, 0, 0);
                            acc[mfh * 2 + mi][nf] = d;
                        }
                    __builtin_amdgcn_s_setprio(0);
                }
                bufc += BUFB; if (bufc == NBUF3) bufc = 0;
            }
        }

        // ---- epilogue (registers only; pipeline continues across it) ----
        // C layout: col = lane&31, row = (reg&3) + 8*(reg>>2) + 4*(lane>>5)
        #pragma unroll
        for (int mf = 0; mf < 4; ++mf) {
            f32x4 iv[4];
            #pragma unroll
            for (int rb = 0; rb < 4; ++rb)
                iv[rb] = *(const f32x4*)&invn_rs[r0 + wr * 128 + mf * 32 + g2 * 4 + rb * 8];
            #pragma unroll
            for (int nf = 0; nf < 2; ++nf)
                #pragma unroll
                for (int reg = 0; reg < 16; ++reg) {
                    int r = r0 + wr * 128 + mf * 32 + (reg & 3) + 8 * (reg >> 2) + 4 * g2;
                    float val = acc[mf][nf][reg] * iv[reg >> 2][reg & 3];
                    if (val > rm[nf] || (val == rm[nf] && r < ra[nf])) { rm[nf] = val; ra[nf] = r; }
                }
        }
    }

    // ---- lane-pair merge (lanes l, l+32 hold same column) ----
    #pragma unroll
    for (int nf = 0; nf < 2; ++nf) {
        float ov = __shfl_xor(rm[nf], 32);
        int   oi = __shfl_xor(ra[nf], 32);
        if (ov > rm[nf] || (ov == rm[nf] && oi < ra[nf])) { rm[nf] = ov; ra[nf] = oi; }
    }
    // ---- cross-wave merge (vmcnt fully drained by last tile's wait) ----
    __syncthreads();
    float* sm2 = (float*)LDSB;          // [2][256]
    int*   si2 = (int*)LDSB + 512;      // [2][256]
    if (lane < 32) {
        #pragma unroll
        for (int nf = 0; nf < 2; ++nf) {
            sm2[wr * 256 + wc * 64 + nf * 32 + l31] = rm[nf];
            si2[wr * 256 + wc * 64 + nf * 32 + l31] = ra[nf];
        }
    }
    __syncthreads();
    if (tid < 256) {
        float bm = sm2[tid]; int ba = si2[tid];
        float v  = sm2[256 + tid]; int a2 = si2[256 + tid];
        if (v > bm || (v == bm && a2 < ba)) { bm = v; ba = a2; }
        int l = l0 + tid;
        int o = (b * SPLITS + by) * LL + l;
        ws[WS_PMAX + o] = bm;
        ((int*)ws)[WS_PARG + o] = ba;
    }
}

// -------- 4) reduce over splits -> s output + final argmax --------
__global__ void k_reduce(float* __restrict__ ws, float* __restrict__ out) {
    int t = blockIdx.x * 256 + threadIdx.x;   // 0..B*L-1
    int b = t >> 12;
    int l = t & (LL - 1);
    float bm = -1e30f; int ba = 0;
    for (int s = 0; s < SPLITS; ++s) {        // splits are ascending r ranges
        int o = (b * SPLITS + s) * LL + l;
        float v = ws[WS_PMAX + o];
        int   a = ((int*)ws)[WS_PARG + o];
        if (v > bm || (v == bm && a < ba)) { bm = v; ba = a; }
    }
    out[t] = bm * ws[WS_INV_LR + t];          // s: [B,1,H,W] flat
    ((int*)ws)[WS_ARG + t] = ba;
}

// -------- 5) gather from ref via argmax + fold(3x3, pad 1) --------
__global__ void k_fold(const float* __restrict__ ref,
                       const float* __restrict__ ws,
                       float* __restrict__ out) {
    int t = blockIdx.x * 256 + threadIdx.x;   // 0..B*C*L-1
    int b = t >> 18;
    int c = (t >> 12) & 63;
    int yx = t & (LL - 1);
    int y = yx >> 6, x = yx & 63;
    const int* ab = ((const int*)ws) + WS_ARG + b * LL;
    const float* rb = ref + (size_t)b * CH * LL + c * LL;
    float s = 0.f;
    #pragma unroll
    for (int i = 0; i < 3; ++i) {
        int yp = y + 1 - i;
        if ((unsigned)yp >= (unsigned)HH) continue;
        #pragma unroll
        for (int j = 0; j < 3; ++j) {
            int xp = x + 1 - j;
            if ((unsigned)xp >= (unsigned)WW) continue;
            int r = ab[yp * WW + xp];
            int ry = (r >> 6) + i - 1;
            int rx = (r & 63) + j - 1;
            if ((unsigned)ry < (unsigned)HH && (unsigned)rx < (unsigned)WW)
                s += rb[ry * WW + rx];
        }
    }
    out[BATCH * LL + t] = s;                  // trans after s (16384 floats)
}

extern "C" void kernel_launch(void* const* d_in, const int* in_sizes, int n_in,
                              void* d_out, int out_size, void* d_ws, size_t ws_size,
                              hipStream_t stream) {
    const float* lrsr = (const float*)d_in[0];
    const float* refsr = (const float*)d_in[1];
    const float* ref  = (const float*)d_in[2];
    float* out = (float*)d_out;
    float* ws  = (float*)d_ws;

    // zero the padded pre-split region (borders must be 0)
    hipMemsetAsync((char*)d_ws + GP_BYTE_BASE, 0, GP_TOTAL, stream);
    k_split<<<dim3(16, 8, 8), dim3(256), 0, stream>>>(lrsr, refsr, ws);
    k_ssq<<<dim3(BATCH * LL / 256), dim3(256), 0, stream>>>(lrsr, refsr, ws);
    k_inv<<<dim3(BATCH * LL / 256), dim3(256), 0, stream>>>(ws);
    k_corrmax<<<dim3(256), dim3(512), 0, stream>>>(ws);
    k_reduce<<<dim3(BATCH * LL / 256), dim3(256), 0, stream>>>(ws, out);
    k_fold<<<dim3(BATCH * CH * LL / 256), dim3(256), 0, stream>>>(ref, ws, out);
}